// Round 4
// baseline (23966.063 us; speedup 1.0000x reference)
//
#include <hip/hip_runtime.h>
#include <cstdint>
#include <cstddef>

namespace {
constexpr int Dh = 512;   // hidden / emb dim
constexpr int G3 = 1536;  // 3*Dh
constexpr int NB = 256;   // batch
constexpr int SL = 256;   // src len
constexpr int TL = 256;   // trg len
constexpr int NV = 512;   // vocab
}

typedef __attribute__((ext_vector_type(8))) short bf16x8;
typedef __attribute__((ext_vector_type(4))) float f32x4;

__device__ __forceinline__ unsigned short f2bf(float f) {
  unsigned int u = __float_as_uint(f);
  u = (u + 0x7FFFu + ((u >> 16) & 1u)) >> 16;  // RNE (finite, small values)
  return (unsigned short)u;
}
__device__ __forceinline__ float bf2f(unsigned short s) {
  return __uint_as_float(((unsigned int)s) << 16);
}

// Permuted gi layout so each recurrence lane reads its 8 j-values (d = w*128 +
// j*16 + l15) as ONE contiguous 16B chunk:
//   [s(256)][b(256)][w(4)][l15(16)][g(3)][j(8)]
__device__ __forceinline__ size_t gi3_off(int s, int b, int g, int d) {
  const int w = d >> 7, l15 = d & 15, j = (d >> 4) & 7;
  return ((((size_t)s * NB + b) * 4 + w) * 16 + l15) * 24 + (size_t)g * 8 + j;
}

// f32 -> bf16 elementwise (optional relu), 4 elems/thread
__global__ __launch_bounds__(256) void cvt_bf16(const float* __restrict__ in,
                                                unsigned short* __restrict__ out,
                                                int n4, int relu) {
  int i = blockIdx.x * 256 + threadIdx.x;
  if (i >= n4) return;
  float4 v = ((const float4*)in)[i];
  if (relu) {
    v.x = fmaxf(v.x, 0.f); v.y = fmaxf(v.y, 0.f);
    v.z = fmaxf(v.z, 0.f); v.w = fmaxf(v.w, 0.f);
  }
  ushort4 o;
  o.x = f2bf(v.x); o.y = f2bf(v.y); o.z = f2bf(v.z); o.w = f2bf(v.w);
  ((ushort4*)out)[i] = o;
}

// C[M,N] = A(bf16) @ W(bf16 [N][K] native rows)^T-as-B + bias, K = 512.
// MFMA 16x16x32. 128x128 tile, BK=64, 4 waves (2x2 x 64x64 quadrants).
// AMODE 0: A row = Abase + idx[row]*K (embedding gather), row m = b*SL + s
// AMODE 1: A row = Abase + ((row&255)*NB + (row>>8))*K (hb_all[t][b], row=b*TL+t)
// OMODE 0: fp32 at row*N+col   OMODE 2: bf16 scattered to gi3 layout
template <int AMODE, int OMODE>
__global__ __launch_bounds__(256) void gemm_bf16(
    const unsigned short* __restrict__ Abase, const int* __restrict__ idx,
    const unsigned short* __restrict__ W, const float* __restrict__ bias,
    void* __restrict__ Cout, int N) {
  __shared__ unsigned short lds_a[8 * 128 * 8];  // 16 KB
  __shared__ unsigned short lds_b[8 * 128 * 8];  // 16 KB
  const int t = threadIdx.x;
  const int n0 = blockIdx.x * 128;
  const int m0 = blockIdx.y * 128;
  const int w = t >> 6, l = t & 63;
  const int mq = (w & 1) * 64, nq = (w >> 1) * 64;
  const int l15 = l & 15, lh = l >> 4;

  const int sm = t & 127;
  const int sk = (t >> 7) * 4;
  const unsigned short* arow;
  if (AMODE == 0) {
    arow = Abase + (size_t)idx[m0 + sm] * Dh;
  } else {
    int row = m0 + sm;
    arow = Abase + ((size_t)(row & 255) * NB + (row >> 8)) * Dh;
  }
  const unsigned short* brow = W + (size_t)(n0 + sm) * Dh;

  f32x4 acc[4][4];
#pragma unroll
  for (int i = 0; i < 4; ++i)
#pragma unroll
    for (int j = 0; j < 4; ++j) acc[i][j] = (f32x4)0.f;

  for (int k0 = 0; k0 < Dh; k0 += 64) {
    __syncthreads();
#pragma unroll
    for (int i = 0; i < 4; ++i) {
      int kc = sk + i;
      *(uint4*)&lds_a[(kc * 128 + sm) * 8] = *(const uint4*)(arow + k0 + kc * 8);
      *(uint4*)&lds_b[(kc * 128 + sm) * 8] = *(const uint4*)(brow + k0 + kc * 8);
    }
    __syncthreads();
#pragma unroll
    for (int q = 0; q < 2; ++q) {
      bf16x8 af[4], bfr[4];
#pragma unroll
      for (int i = 0; i < 4; ++i)
        af[i] = *(const bf16x8*)&lds_a[((q * 4 + lh) * 128 + mq + i * 16 + l15) * 8];
#pragma unroll
      for (int j = 0; j < 4; ++j)
        bfr[j] = *(const bf16x8*)&lds_b[((q * 4 + lh) * 128 + nq + j * 16 + l15) * 8];
#pragma unroll
      for (int i = 0; i < 4; ++i)
#pragma unroll
        for (int j = 0; j < 4; ++j)
          acc[i][j] = __builtin_amdgcn_mfma_f32_16x16x32_bf16(af[i], bfr[j], acc[i][j], 0, 0, 0);
    }
  }

#pragma unroll
  for (int j = 0; j < 4; ++j) {
    const int col = n0 + nq + j * 16 + l15;
    const float bv = bias[col];
#pragma unroll
    for (int i = 0; i < 4; ++i) {
#pragma unroll
      for (int r = 0; r < 4; ++r) {
        const int row = m0 + mq + i * 16 + lh * 4 + r;
        const float v = acc[i][j][r] + bv;
        if (OMODE == 0) {
          ((float*)Cout)[(size_t)row * N + col] = v;
        } else {
          const int b = row >> 8, s = row & 255;      // row = b*SL + s
          const int g = col >> 9, d = col & 511;
          ((unsigned short*)Cout)[gi3_off(s, b, g, d)] = f2bf(v);
        }
      }
    }
  }
}

// Persistent WG-local GRU: grid = NB/16 = 16 WGs, NO inter-WG sync.
// WG owns 16 batches x all 512 d; loops nsteps with only __syncthreads.
// Wave w owns d-range [w*128, (w+1)*128) for ALL 3 gates -> gate math lane-local.
// Whh streamed from L2 each step; h: fp32 in regs + bf16 in LDS.
__global__ __launch_bounds__(256, 1) void gru_local(
    const unsigned short* __restrict__ W,    // Whh bf16 [1536][512] native
    const unsigned short* __restrict__ gi3,  // permuted gi (incl. bih)
    const float* __restrict__ bhh,
    const float* __restrict__ h0_in,         // fp32 [NB][Dh] (null -> zeros)
    float* __restrict__ h_final,             // fp32 out (or null)
    unsigned short* __restrict__ hb_all,     // [s][b][d] archive (or null)
    int nsteps) {
  __shared__ unsigned short hlds[64 * 16 * 8];  // [kc(64)][b(16)][8] = 16 KB
  const int t = threadIdx.x;
  const int b0 = blockIdx.x * 16;
  const int w = t >> 6, l = t & 63;
  const int l15 = l & 15, lh = l >> 4;

  // biases for this lane's d-columns (b-independent)
  float br_[8], bz_[8], bn_[8];
#pragma unroll
  for (int j = 0; j < 8; ++j) {
    const int d = w * 128 + j * 16 + l15;
    br_[j] = bhh[d]; bz_[j] = bhh[Dh + d]; bn_[j] = bhh[2 * Dh + d];
  }

  // init h (fp32 regs [j][r]) + bf16 LDS mirror
  float hreg[8][4];
#pragma unroll
  for (int j = 0; j < 8; ++j)
#pragma unroll
    for (int r = 0; r < 4; ++r) {
      const int d = w * 128 + j * 16 + l15;
      const int bl = lh * 4 + r;
      float v = h0_in ? h0_in[(size_t)(b0 + bl) * Dh + d] : 0.f;
      hreg[j][r] = v;
      hlds[((w * 16 + j * 2 + (l15 >> 3)) * 16 + bl) * 8 + (l15 & 7)] = f2bf(v);
    }

  // gi prefetch registers: gp[r*3+g] = 8 j-values (ushort8)
  uint4 gp[12];
#pragma unroll
  for (int r = 0; r < 4; ++r)
#pragma unroll
    for (int g = 0; g < 3; ++g) {
      const int b = b0 + lh * 4 + r;
      gp[r * 3 + g] = *(const uint4*)(gi3 + ((((size_t)0 * NB + b) * 4 + w) * 16 + l15) * 24 + g * 8);
    }

  const unsigned short* const Wl = W + ((size_t)w * 128 + l15) * Dh + lh * 8;
  __syncthreads();

  for (int s = 0; s < nsteps; ++s) {
    // A-fragments for all 16 k-steps (k = (kk*4+lh)*8 ..+8)
    bf16x8 af[16];
#pragma unroll
    for (int kk = 0; kk < 16; ++kk)
      af[kk] = *(const bf16x8*)&hlds[((kk * 4 + lh) * 16 + l15) * 8];

    f32x4 acc[3][8];
#pragma unroll
    for (int g = 0; g < 3; ++g)
#pragma unroll
      for (int j = 0; j < 8; ++j) acc[g][j] = (f32x4)0.f;

#pragma unroll
    for (int g = 0; g < 3; ++g)
#pragma unroll
      for (int j = 0; j < 8; ++j) {
        const unsigned short* bp = Wl + ((size_t)g * 512 + j * 16) * Dh;
#pragma unroll
        for (int kk = 0; kk < 16; ++kk) {
          bf16x8 bv = *(const bf16x8*)(bp + kk * 32);
          acc[g][j] = __builtin_amdgcn_mfma_f32_16x16x32_bf16(af[kk], bv, acc[g][j], 0, 0, 0);
        }
      }

    // gates: everything lane-local. D row = lh*4+r (batch), col = l15 (within d-tile)
#pragma unroll
    for (int j = 0; j < 8; ++j)
#pragma unroll
      for (int r = 0; r < 4; ++r) {
        const float gir = bf2f(((const unsigned short*)&gp[r * 3 + 0])[j]);
        const float giz = bf2f(((const unsigned short*)&gp[r * 3 + 1])[j]);
        const float gin = bf2f(((const unsigned short*)&gp[r * 3 + 2])[j]);
        const float rr = 1.f / (1.f + __expf(-(gir + acc[0][j][r] + br_[j])));
        const float zz = 1.f / (1.f + __expf(-(giz + acc[1][j][r] + bz_[j])));
        const float x2 = gin + rr * (acc[2][j][r] + bn_[j]);
        const float nn = 1.f - 2.f / (__expf(2.f * x2) + 1.f);  // tanh
        hreg[j][r] = (1.f - zz) * nn + zz * hreg[j][r];
      }

    __syncthreads();  // all af reads of hlds complete -> safe to overwrite

#pragma unroll
    for (int j = 0; j < 8; ++j)
#pragma unroll
      for (int r = 0; r < 4; ++r) {
        const int d = w * 128 + j * 16 + l15;
        const int bl = lh * 4 + r;
        const unsigned short hb = f2bf(hreg[j][r]);
        hlds[((w * 16 + j * 2 + (l15 >> 3)) * 16 + bl) * 8 + (l15 & 7)] = hb;
        if (hb_all) hb_all[((size_t)s * NB + b0 + bl) * Dh + d] = hb;
      }

    if (h_final && s == nsteps - 1) {
#pragma unroll
      for (int j = 0; j < 8; ++j)
#pragma unroll
        for (int r = 0; r < 4; ++r) {
          const int d = w * 128 + j * 16 + l15;
          h_final[(size_t)(b0 + lh * 4 + r) * Dh + d] = hreg[j][r];
        }
    }

    if (s + 1 < nsteps) {  // prefetch next step's gi (hidden under next MFMA phase)
#pragma unroll
      for (int r = 0; r < 4; ++r)
#pragma unroll
        for (int g = 0; g < 3; ++g) {
          const int b = b0 + lh * 4 + r;
          gp[r * 3 + g] = *(const uint4*)(gi3 + ((((size_t)(s + 1) * NB + b) * 4 + w) * 16 + l15) * 24 + g * 8);
        }
    }

    __syncthreads();  // hlds writes visible before next step's af reads
  }
}

// in-place log_softmax over last dim (512); one wave per row
__global__ __launch_bounds__(256) void logsoftmax512(float* __restrict__ x) {
  const int row = blockIdx.x * 4 + (threadIdx.x >> 6);
  const int lane = threadIdx.x & 63;
  float* p = x + (size_t)row * NV + lane * 8;
  float4 v0 = *(const float4*)p;
  float4 v1 = *(const float4*)(p + 4);
  float m = fmaxf(fmaxf(fmaxf(v0.x, v0.y), fmaxf(v0.z, v0.w)),
                  fmaxf(fmaxf(v1.x, v1.y), fmaxf(v1.z, v1.w)));
#pragma unroll
  for (int o = 1; o < 64; o <<= 1) m = fmaxf(m, __shfl_xor(m, o, 64));
  float s = expf(v0.x - m) + expf(v0.y - m) + expf(v0.z - m) + expf(v0.w - m) +
            expf(v1.x - m) + expf(v1.y - m) + expf(v1.z - m) + expf(v1.w - m);
#pragma unroll
  for (int o = 1; o < 64; o <<= 1) s += __shfl_xor(s, o, 64);
  const float ls = m + logf(s);
  v0.x -= ls; v0.y -= ls; v0.z -= ls; v0.w -= ls;
  v1.x -= ls; v1.y -= ls; v1.z -= ls; v1.w -= ls;
  *(float4*)p = v0;
  *(float4*)(p + 4) = v1;
}

extern "C" void kernel_launch(void* const* d_in, const int* in_sizes, int n_in,
                              void* d_out, int out_size, void* d_ws, size_t ws_size,
                              hipStream_t stream) {
  (void)in_sizes; (void)n_in; (void)out_size; (void)ws_size;
  const int* src = (const int*)d_in[0];
  const int* trg = (const int*)d_in[1];
  const float* enc_emb = (const float*)d_in[4];
  const float* enc_Wih = (const float*)d_in[5];
  const float* enc_Whh = (const float*)d_in[6];
  const float* enc_bih = (const float*)d_in[7];
  const float* enc_bhh = (const float*)d_in[8];
  const float* dec_emb = (const float*)d_in[9];
  const float* dec_Wih = (const float*)d_in[10];
  const float* dec_Whh = (const float*)d_in[11];
  const float* dec_bih = (const float*)d_in[12];
  const float* dec_bhh = (const float*)d_in[13];
  const float* out_W = (const float*)d_in[14];
  const float* out_b = (const float*)d_in[15];

  char* ws = (char*)d_ws;
  size_t off = 0;
  auto alloc = [&](size_t bytes) -> char* {
    char* p = ws + off;
    off += (bytes + 255) & ~(size_t)255;
    return p;
  };
  typedef unsigned short u16;
  u16* gi = (u16*)alloc((size_t)NB * SL * G3 * 2);      // 201 MB (enc, then dec)
  u16* hb_all = (u16*)alloc((size_t)TL * NB * Dh * 2);  // 67 MB decoder bf16 h
  float* h_enc = (float*)alloc((size_t)NB * Dh * 4);
  u16* embB_e = (u16*)alloc((size_t)NV * Dh * 2);
  u16* embB_d = (u16*)alloc((size_t)NV * Dh * 2);       // relu pre-applied
  u16* WihB_e = (u16*)alloc((size_t)G3 * Dh * 2);
  u16* WhhB_e = (u16*)alloc((size_t)G3 * Dh * 2);
  u16* WihB_d = (u16*)alloc((size_t)G3 * Dh * 2);
  u16* WhhB_d = (u16*)alloc((size_t)G3 * Dh * 2);
  u16* outWB = (u16*)alloc((size_t)NV * Dh * 2);

  cvt_bf16<<<(NV * Dh / 4 + 255) / 256, 256, 0, stream>>>(enc_emb, embB_e, NV * Dh / 4, 0);
  cvt_bf16<<<(NV * Dh / 4 + 255) / 256, 256, 0, stream>>>(dec_emb, embB_d, NV * Dh / 4, 1);
  cvt_bf16<<<(G3 * Dh / 4 + 255) / 256, 256, 0, stream>>>(enc_Wih, WihB_e, G3 * Dh / 4, 0);
  cvt_bf16<<<(G3 * Dh / 4 + 255) / 256, 256, 0, stream>>>(enc_Whh, WhhB_e, G3 * Dh / 4, 0);
  cvt_bf16<<<(G3 * Dh / 4 + 255) / 256, 256, 0, stream>>>(dec_Wih, WihB_d, G3 * Dh / 4, 0);
  cvt_bf16<<<(G3 * Dh / 4 + 255) / 256, 256, 0, stream>>>(dec_Whh, WhhB_d, G3 * Dh / 4, 0);
  cvt_bf16<<<(NV * Dh / 4 + 255) / 256, 256, 0, stream>>>(out_W, outWB, NV * Dh / 4, 0);

  // encoder gi (permuted gi3 layout)
  dim3 ggi(G3 / 128, NB * SL / 128);
  gemm_bf16<0, 2><<<ggi, 256, 0, stream>>>(embB_e, src, WihB_e, enc_bih, gi, G3);

  // encoder recurrence: 16 independent persistent WGs, no grid sync
  gru_local<<<dim3(NB / 16), 256, 0, stream>>>(WhhB_e, gi, enc_bhh, nullptr, h_enc, nullptr, SL);

  // decoder gi (reuses buffer; stream-ordered after encoder finished reading)
  gemm_bf16<0, 2><<<ggi, 256, 0, stream>>>(embB_d, trg, WihB_d, dec_bih, gi, G3);

  // decoder recurrence
  gru_local<<<dim3(NB / 16), 256, 0, stream>>>(WhhB_d, gi, dec_bhh, h_enc, nullptr, hb_all, TL);

  // logits = hb_all @ out_W^T + out_b -> d_out (fp32), then log_softmax
  dim3 glg(NV / 128, NB * TL / 128);
  gemm_bf16<1, 0><<<glg, 256, 0, stream>>>(hb_all, nullptr, outWB, out_b, d_out, NV);
  logsoftmax512<<<NB * TL / 4, 256, 0, stream>>>((float*)d_out);
}

// Round 5
// 6868.732 us; speedup vs baseline: 3.4892x; 3.4892x over previous
//
#include <hip/hip_runtime.h>
#include <cstdint>
#include <cstddef>

namespace {
constexpr int Dh = 512;   // hidden / emb dim
constexpr int G3 = 1536;  // 3*Dh
constexpr int NB = 256;   // batch
constexpr int SL = 256;   // src len
constexpr int TL = 256;   // trg len
constexpr int NV = 512;   // vocab
}

typedef __attribute__((ext_vector_type(8))) short bf16x8;
typedef __attribute__((ext_vector_type(4))) float f32x4;

__device__ __forceinline__ unsigned short f2bf(float f) {
  unsigned int u = __float_as_uint(f);
  u = (u + 0x7FFFu + ((u >> 16) & 1u)) >> 16;  // RNE (finite, small values)
  return (unsigned short)u;
}
__device__ __forceinline__ float bf2f(unsigned short s) {
  return __uint_as_float(((unsigned int)s) << 16);
}

// gi packed layout (consumer-native): [s][b][dt32(16)][l15(16)][8]
// slot n*3+g (n = d16-half within 32-d tile, g = gate), slots 6,7 padding.
// One 16B load gives a lane all 6 gate values for (b, d-tile, col l15).

// f32 -> bf16 elementwise (optional relu), 4 elems/thread
__global__ __launch_bounds__(256) void cvt_bf16(const float* __restrict__ in,
                                                unsigned short* __restrict__ out,
                                                int n4, int relu) {
  int i = blockIdx.x * 256 + threadIdx.x;
  if (i >= n4) return;
  float4 v = ((const float4*)in)[i];
  if (relu) {
    v.x = fmaxf(v.x, 0.f); v.y = fmaxf(v.y, 0.f);
    v.z = fmaxf(v.z, 0.f); v.w = fmaxf(v.w, 0.f);
  }
  ushort4 o;
  o.x = f2bf(v.x); o.y = f2bf(v.y); o.z = f2bf(v.z); o.w = f2bf(v.w);
  ((ushort4*)out)[i] = o;
}

// C[M,N] = A(bf16) @ W(bf16 [N][K] native rows)^T-as-B + bias, K = 512.
// MFMA 16x16x32. 128x128 tile, BK=64, 4 waves (2x2 x 64x64 quadrants).
// AMODE 0: A row = Abase + idx[row]*K (embedding gather), row m = b*256 + s
// AMODE 1: A row = Abase + ((row&255)*NB + (row>>8))*K (hb_all[t][b], row=b*TL+t)
// OMODE 0: fp32 at row*N+col   OMODE 2: bf16 scattered to packed gi layout
template <int AMODE, int OMODE>
__global__ __launch_bounds__(256) void gemm_bf16(
    const unsigned short* __restrict__ Abase, const int* __restrict__ idx,
    const unsigned short* __restrict__ W, const float* __restrict__ bias,
    void* __restrict__ Cout, int N) {
  __shared__ unsigned short lds_a[8 * 128 * 8];  // 16 KB
  __shared__ unsigned short lds_b[8 * 128 * 8];  // 16 KB
  const int t = threadIdx.x;
  const int n0 = blockIdx.x * 128;
  const int m0 = blockIdx.y * 128;
  const int w = t >> 6, l = t & 63;
  const int mq = (w & 1) * 64, nq = (w >> 1) * 64;
  const int l15 = l & 15, lh = l >> 4;

  const int sm = t & 127;
  const int sk = (t >> 7) * 4;
  const unsigned short* arow;
  if (AMODE == 0) {
    arow = Abase + (size_t)idx[m0 + sm] * Dh;
  } else {
    int row = m0 + sm;
    arow = Abase + ((size_t)(row & 255) * NB + (row >> 8)) * Dh;
  }
  const unsigned short* brow = W + (size_t)(n0 + sm) * Dh;

  f32x4 acc[4][4];
#pragma unroll
  for (int i = 0; i < 4; ++i)
#pragma unroll
    for (int j = 0; j < 4; ++j) acc[i][j] = (f32x4)0.f;

  for (int k0 = 0; k0 < Dh; k0 += 64) {
    __syncthreads();
#pragma unroll
    for (int i = 0; i < 4; ++i) {
      int kc = sk + i;
      *(uint4*)&lds_a[(kc * 128 + sm) * 8] = *(const uint4*)(arow + k0 + kc * 8);
      *(uint4*)&lds_b[(kc * 128 + sm) * 8] = *(const uint4*)(brow + k0 + kc * 8);
    }
    __syncthreads();
#pragma unroll
    for (int q = 0; q < 2; ++q) {
      bf16x8 af[4], bfr[4];
#pragma unroll
      for (int i = 0; i < 4; ++i)
        af[i] = *(const bf16x8*)&lds_a[((q * 4 + lh) * 128 + mq + i * 16 + l15) * 8];
#pragma unroll
      for (int j = 0; j < 4; ++j)
        bfr[j] = *(const bf16x8*)&lds_b[((q * 4 + lh) * 128 + nq + j * 16 + l15) * 8];
#pragma unroll
      for (int i = 0; i < 4; ++i)
#pragma unroll
        for (int j = 0; j < 4; ++j)
          acc[i][j] = __builtin_amdgcn_mfma_f32_16x16x32_bf16(af[i], bfr[j], acc[i][j], 0, 0, 0);
    }
  }

#pragma unroll
  for (int j = 0; j < 4; ++j) {
    const int col = n0 + nq + j * 16 + l15;
    const float bv = bias[col];
#pragma unroll
    for (int i = 0; i < 4; ++i) {
#pragma unroll
      for (int r = 0; r < 4; ++r) {
        const int row = m0 + mq + i * 16 + lh * 4 + r;
        const float v = acc[i][j][r] + bv;
        if (OMODE == 0) {
          ((float*)Cout)[(size_t)row * N + col] = v;
        } else {
          const int b = row >> 8, s = row & 255;      // row = b*256 + s
          const int g = col >> 9, d = col & 511;
          const int dt = d >> 5, nn_ = (d >> 4) & 1, cl = d & 15;
          ((unsigned short*)Cout)[((((size_t)s * NB + b) * 16 + dt) * 16 + cl) * 8 + nn_ * 3 + g] = f2bf(v);
        }
      }
    }
  }
}

// ---- shared wave-tile GRU core: wave owns 16b x 32d x 3 gates, K=512 ----
// 96 MFMA + 96 independent B-loads (pipelined), gates lane-local, no LDS.
// D mapping: row (batch) = lh*4+r, col (d within 16) = l15.
__device__ __forceinline__ void gru_wave_tile(
    const unsigned short* __restrict__ W, const unsigned short* __restrict__ gi,
    const float* __restrict__ bhh, const unsigned short* __restrict__ hb_in,
    int s, int b0, int d0, int l15, int lh,
    const float hp[2][4],  // fp32 h carry for (n, r)
    float o[2][4]) {
  // A-fragments: h rows b0+l15, k = kk*32 + lh*8
  bf16x8 af[16];
#pragma unroll
  for (int kk = 0; kk < 16; ++kk)
    af[kk] = *(const bf16x8*)(hb_in + (size_t)(b0 + l15) * Dh + kk * 32 + lh * 8);

  // gi packed loads: one uint4 per r
  uint4 gpr[4];
#pragma unroll
  for (int r = 0; r < 4; ++r)
    gpr[r] = *(const uint4*)(gi + ((((size_t)s * NB + b0 + lh * 4 + r) * 16 + (d0 >> 5)) * 16 + l15) * 8);

  f32x4 acc[2][3];
#pragma unroll
  for (int n = 0; n < 2; ++n)
#pragma unroll
    for (int g = 0; g < 3; ++g) acc[n][g] = (f32x4)0.f;

#pragma unroll
  for (int n = 0; n < 2; ++n)
#pragma unroll
    for (int g = 0; g < 3; ++g) {
      const unsigned short* bp = W + (size_t)(g * 512 + d0 + n * 16 + l15) * Dh + lh * 8;
      bf16x8 bv[16];
#pragma unroll
      for (int kk = 0; kk < 16; ++kk) bv[kk] = *(const bf16x8*)(bp + kk * 32);
#pragma unroll
      for (int kk = 0; kk < 16; ++kk)
        acc[n][g] = __builtin_amdgcn_mfma_f32_16x16x32_bf16(af[kk], bv[kk], acc[n][g], 0, 0, 0);
    }

#pragma unroll
  for (int n = 0; n < 2; ++n) {
    const int d = d0 + n * 16 + l15;
    const float br = bhh[d], bz = bhh[512 + d], bn = bhh[1024 + d];
#pragma unroll
    for (int r = 0; r < 4; ++r) {
      const unsigned short* gp = (const unsigned short*)&gpr[r];
      const float gir = bf2f(gp[n * 3 + 0]);
      const float giz = bf2f(gp[n * 3 + 1]);
      const float gin = bf2f(gp[n * 3 + 2]);
      const float rr = 1.f / (1.f + __expf(-(gir + acc[n][0][r] + br)));
      const float zz = 1.f / (1.f + __expf(-(giz + acc[n][1][r] + bz)));
      const float x2 = gin + rr * (acc[n][2][r] + bn);
      const float nn = 1.f - 2.f / (__expf(2.f * x2) + 1.f);  // tanh
      o[n][r] = (1.f - zz) * nn + zz * hp[n][r];
    }
  }
}

// ---- S1-lean: one GRU step per launch. 64 WGs x 256 thr = 256 waves. ----
__global__ __launch_bounds__(256, 1) void gru_step2(
    const unsigned short* __restrict__ W, const unsigned short* __restrict__ gi,
    const float* __restrict__ bhh,
    const float* __restrict__ h32_in, float* __restrict__ h32_out,
    const unsigned short* __restrict__ hb_in, unsigned short* __restrict__ hb_out,
    int s) {
  const int t = threadIdx.x;
  const int wt = blockIdx.x * 4 + (t >> 6);
  const int b0 = (wt >> 4) * 16, d0 = (wt & 15) * 32;
  const int l = t & 63, l15 = l & 15, lh = l >> 4;

  float hp[2][4], o[2][4];
#pragma unroll
  for (int n = 0; n < 2; ++n)
#pragma unroll
    for (int r = 0; r < 4; ++r)
      hp[n][r] = h32_in[(size_t)(b0 + lh * 4 + r) * Dh + d0 + n * 16 + l15];

  gru_wave_tile(W, gi, bhh, hb_in, s, b0, d0, l15, lh, hp, o);

#pragma unroll
  for (int n = 0; n < 2; ++n)
#pragma unroll
    for (int r = 0; r < 4; ++r) {
      const int b = b0 + lh * 4 + r, d = d0 + n * 16 + l15;
      h32_out[(size_t)b * Dh + d] = o[n][r];
      hb_out[(size_t)b * Dh + d] = f2bf(o[n][r]);
    }
}

// ---- S2-persistent: whole phase in one kernel, 4-WG sibling sync. ----
// 64 WGs = 16 groups (16 batches each) x 4 d-quadrant WGs. fp32 h in regs.
__global__ __launch_bounds__(256, 1) void gru_persist(
    const unsigned short* __restrict__ W, const unsigned short* __restrict__ gi,
    const float* __restrict__ bhh,
    unsigned short* __restrict__ hg0, unsigned short* __restrict__ hg1,
    float* __restrict__ h_final, unsigned int* __restrict__ flags,
    int nsteps) {
  const int t = threadIdx.x;
  const int bid = blockIdx.x;
  const int wt = bid * 4 + (t >> 6);
  const int b0 = (wt >> 4) * 16, d0 = (wt & 15) * 32;
  const int l = t & 63, l15 = l & 15, lh = l >> 4;

  float hp[2][4], o[2][4];
#pragma unroll
  for (int n = 0; n < 2; ++n)
#pragma unroll
    for (int r = 0; r < 4; ++r) hp[n][r] = 0.f;

  for (int s = 0; s < nsteps; ++s) {
    const unsigned short* hbi = (s & 1) ? hg1 : hg0;
    unsigned short* hbo = (s & 1) ? hg0 : hg1;

    gru_wave_tile(W, gi, bhh, hbi, s, b0, d0, l15, lh, hp, o);

#pragma unroll
    for (int n = 0; n < 2; ++n)
#pragma unroll
      for (int r = 0; r < 4; ++r) {
        const int b = b0 + lh * 4 + r, d = d0 + n * 16 + l15;
        hbo[(size_t)b * Dh + d] = f2bf(o[n][r]);
        hp[n][r] = o[n][r];
      }

    if (s + 1 < nsteps) {
      // sibling-group sync: all WG stores drained by the barrier's vmcnt(0);
      // t0 publishes with one release fence, spins RELAXED (no per-iter inv),
      // one acquire fence after success.
      __syncthreads();
      if (t == 0) {
        __builtin_amdgcn_fence(__ATOMIC_RELEASE, "agent");
        __hip_atomic_store(&flags[bid * 16], (unsigned)(s + 1), __ATOMIC_RELAXED,
                           __HIP_MEMORY_SCOPE_AGENT);
        const int base = bid & ~3;
#pragma unroll
        for (int k = 0; k < 4; ++k) {
          if (base + k == bid) continue;
          while (__hip_atomic_load(&flags[(base + k) * 16], __ATOMIC_RELAXED,
                                   __HIP_MEMORY_SCOPE_AGENT) < (unsigned)(s + 1))
            __builtin_amdgcn_s_sleep(2);
        }
        __builtin_amdgcn_fence(__ATOMIC_ACQUIRE, "agent");
      }
      __syncthreads();
    }
  }

#pragma unroll
  for (int n = 0; n < 2; ++n)
#pragma unroll
    for (int r = 0; r < 4; ++r) {
      const int b = b0 + lh * 4 + r, d = d0 + n * 16 + l15;
      h_final[(size_t)b * Dh + d] = hp[n][r];
    }
}

// in-place log_softmax over last dim (512); one wave per row
__global__ __launch_bounds__(256) void logsoftmax512(float* __restrict__ x) {
  const int row = blockIdx.x * 4 + (threadIdx.x >> 6);
  const int lane = threadIdx.x & 63;
  float* p = x + (size_t)row * NV + lane * 8;
  float4 v0 = *(const float4*)p;
  float4 v1 = *(const float4*)(p + 4);
  float m = fmaxf(fmaxf(fmaxf(v0.x, v0.y), fmaxf(v0.z, v0.w)),
                  fmaxf(fmaxf(v1.x, v1.y), fmaxf(v1.z, v1.w)));
#pragma unroll
  for (int o = 1; o < 64; o <<= 1) m = fmaxf(m, __shfl_xor(m, o, 64));
  float s = expf(v0.x - m) + expf(v0.y - m) + expf(v0.z - m) + expf(v0.w - m) +
            expf(v1.x - m) + expf(v1.y - m) + expf(v1.z - m) + expf(v1.w - m);
#pragma unroll
  for (int o = 1; o < 64; o <<= 1) s += __shfl_xor(s, o, 64);
  const float ls = m + logf(s);
  v0.x -= ls; v0.y -= ls; v0.z -= ls; v0.w -= ls;
  v1.x -= ls; v1.y -= ls; v1.z -= ls; v1.w -= ls;
  *(float4*)p = v0;
  *(float4*)(p + 4) = v1;
}

extern "C" void kernel_launch(void* const* d_in, const int* in_sizes, int n_in,
                              void* d_out, int out_size, void* d_ws, size_t ws_size,
                              hipStream_t stream) {
  (void)in_sizes; (void)n_in; (void)out_size; (void)ws_size;
  const int* src = (const int*)d_in[0];
  const int* trg = (const int*)d_in[1];
  const float* enc_emb = (const float*)d_in[4];
  const float* enc_Wih = (const float*)d_in[5];
  const float* enc_Whh = (const float*)d_in[6];
  const float* enc_bih = (const float*)d_in[7];
  const float* enc_bhh = (const float*)d_in[8];
  const float* dec_emb = (const float*)d_in[9];
  const float* dec_Wih = (const float*)d_in[10];
  const float* dec_Whh = (const float*)d_in[11];
  const float* dec_bih = (const float*)d_in[12];
  const float* dec_bhh = (const float*)d_in[13];
  const float* out_W = (const float*)d_in[14];
  const float* out_b = (const float*)d_in[15];

  char* ws = (char*)d_ws;
  size_t off = 0;
  auto alloc = [&](size_t bytes) -> char* {
    char* p = ws + off;
    off += (bytes + 255) & ~(size_t)255;
    return p;
  };
  typedef unsigned short u16;
  u16* gi = (u16*)alloc((size_t)NB * SL * 16 * 16 * 8 * 2);  // 268 MB packed
  u16* hb_all = (u16*)alloc((size_t)TL * NB * Dh * 2);       // 67 MB
  float* h_enc = (float*)alloc((size_t)NB * Dh * 4);
  float* h32a = (float*)alloc((size_t)NB * Dh * 4);
  float* h32b = (float*)alloc((size_t)NB * Dh * 4);
  u16* hg0 = (u16*)alloc((size_t)NB * Dh * 2);
  u16* hg1 = (u16*)alloc((size_t)NB * Dh * 2);
  u16* embB_e = (u16*)alloc((size_t)NV * Dh * 2);
  u16* embB_d = (u16*)alloc((size_t)NV * Dh * 2);            // relu pre-applied
  u16* WihB_e = (u16*)alloc((size_t)G3 * Dh * 2);
  u16* WhhB_e = (u16*)alloc((size_t)G3 * Dh * 2);
  u16* WihB_d = (u16*)alloc((size_t)G3 * Dh * 2);
  u16* WhhB_d = (u16*)alloc((size_t)G3 * Dh * 2);
  u16* outWB = (u16*)alloc((size_t)NV * Dh * 2);
  unsigned int* flags = (unsigned int*)alloc(64 * 16 * 4);

  cvt_bf16<<<(NV * Dh / 4 + 255) / 256, 256, 0, stream>>>(enc_emb, embB_e, NV * Dh / 4, 0);
  cvt_bf16<<<(NV * Dh / 4 + 255) / 256, 256, 0, stream>>>(dec_emb, embB_d, NV * Dh / 4, 1);
  cvt_bf16<<<(G3 * Dh / 4 + 255) / 256, 256, 0, stream>>>(enc_Wih, WihB_e, G3 * Dh / 4, 0);
  cvt_bf16<<<(G3 * Dh / 4 + 255) / 256, 256, 0, stream>>>(enc_Whh, WhhB_e, G3 * Dh / 4, 0);
  cvt_bf16<<<(G3 * Dh / 4 + 255) / 256, 256, 0, stream>>>(dec_Wih, WihB_d, G3 * Dh / 4, 0);
  cvt_bf16<<<(G3 * Dh / 4 + 255) / 256, 256, 0, stream>>>(dec_Whh, WhhB_d, G3 * Dh / 4, 0);
  cvt_bf16<<<(NV * Dh / 4 + 255) / 256, 256, 0, stream>>>(out_W, outWB, NV * Dh / 4, 0);
  hipMemsetAsync(hg0, 0, (size_t)NB * Dh * 2, stream);   // bf16 h0 = 0
  hipMemsetAsync(flags, 0, 64 * 16 * 4, stream);

  // encoder gi (packed layout)
  dim3 ggi(G3 / 128, NB * SL / 128);
  gemm_bf16<0, 2><<<ggi, 256, 0, stream>>>(embB_e, src, WihB_e, enc_bih, gi, G3);

  // ---- encoder recurrence: S2-persistent (A/B arm 1) ----
  gru_persist<<<dim3(64), 256, 0, stream>>>(WhhB_e, gi, enc_bhh, hg0, hg1, h_enc, flags, SL);
  // final bf16 h is in buf[(255+1)&1] = hg0

  // decoder gi (packed layout; stream-ordered after encoder reads done)
  gemm_bf16<0, 2><<<ggi, 256, 0, stream>>>(embB_d, trg, WihB_d, dec_bih, gi, G3);

  // ---- decoder recurrence: S1-lean per-step launches (A/B arm 2) ----
  for (int s = 0; s < TL; ++s) {
    const float* hin32 = (s == 0) ? h_enc : ((s & 1) ? h32b : h32a);
    float* hout32 = (s & 1) ? h32a : h32b;
    const u16* hbi = (s == 0) ? hg0 : (hb_all + (size_t)(s - 1) * NB * Dh);
    u16* hbo = hb_all + (size_t)s * NB * Dh;
    gru_step2<<<dim3(64), 256, 0, stream>>>(WhhB_d, gi, dec_bhh, hin32, hout32, hbi, hbo, s);
  }

  // logits = hb_all @ out_W^T + out_b -> d_out (fp32), then log_softmax
  dim3 glg(NV / 128, NB * TL / 128);
  gemm_bf16<1, 0><<<glg, 256, 0, stream>>>(hb_all, nullptr, outWB, out_b, d_out, NV);
  logsoftmax512<<<NB * TL / 4, 256, 0, stream>>>((float*)d_out);
}

// Round 6
// 3939.071 us; speedup vs baseline: 6.0842x; 1.7437x over previous
//
#include <hip/hip_runtime.h>
#include <cstdint>
#include <cstddef>

namespace {
constexpr int Dh = 512;   // hidden / emb dim
constexpr int G3 = 1536;  // 3*Dh
constexpr int NB = 256;   // batch
constexpr int SL = 256;   // src len
constexpr int TL = 256;   // trg len
constexpr int NV = 512;   // vocab
}

typedef __attribute__((ext_vector_type(8))) short bf16x8;
typedef __attribute__((ext_vector_type(4))) float f32x4;

__device__ __forceinline__ unsigned short f2bf(float f) {
  unsigned int u = __float_as_uint(f);
  u = (u + 0x7FFFu + ((u >> 16) & 1u)) >> 16;  // RNE (finite, small values)
  return (unsigned short)u;
}
__device__ __forceinline__ float bf2f(unsigned short s) {
  return __uint_as_float(((unsigned int)s) << 16);
}

// gi packed layout (consumer-native): [s][b][dt32(16)][l15(16)][8]
// slot n*3+g (n = d16-half within 32-d tile, g = gate), slots 6,7 padding.

// f32 -> bf16 elementwise (optional relu), 4 elems/thread
__global__ __launch_bounds__(256) void cvt_bf16(const float* __restrict__ in,
                                                unsigned short* __restrict__ out,
                                                int n4, int relu) {
  int i = blockIdx.x * 256 + threadIdx.x;
  if (i >= n4) return;
  float4 v = ((const float4*)in)[i];
  if (relu) {
    v.x = fmaxf(v.x, 0.f); v.y = fmaxf(v.y, 0.f);
    v.z = fmaxf(v.z, 0.f); v.w = fmaxf(v.w, 0.f);
  }
  ushort4 o;
  o.x = f2bf(v.x); o.y = f2bf(v.y); o.z = f2bf(v.z); o.w = f2bf(v.w);
  ((ushort4*)out)[i] = o;
}

// Pack Whh (bf16 [1536][512] native) into lane-major fragment order:
// Wpk[dt(16)][slot(6)][kk(16)][lane(64)][8], slot = n*3+g.
// Fragment (dt,slot,kk,lane): W[g*512 + dt*32 + n*16 + (l&15)][kk*32 + (l>>4)*8 .. +8]
__global__ __launch_bounds__(256) void pack_whh(const unsigned short* __restrict__ Wb,
                                                unsigned short* __restrict__ Wpk) {
  const int idx = blockIdx.x * 256 + threadIdx.x;  // 16*6*16*64 = 98304 fragments
  if (idx >= 16 * 6 * 16 * 64) return;
  const int dt = idx / 6144;
  const int rem = idx - dt * 6144;
  const int slot = rem >> 10;
  const int kk = (rem >> 6) & 15;
  const int l = rem & 63;
  const int n = slot / 3, g = slot - n * 3;
  const int row = g * 512 + dt * 32 + n * 16 + (l & 15);
  const int k = kk * 32 + (l >> 4) * 8;
  *(uint4*)(Wpk + (size_t)idx * 8) = *(const uint4*)(Wb + (size_t)row * Dh + k);
}

// C[M,N] = A(bf16) @ W(bf16 [N][K] native rows)^T-as-B + bias, K = 512.
// MFMA 16x16x32. 128x128 tile, BK=64, 4 waves (2x2 x 64x64 quadrants).
// AMODE 0: A row = Abase + idx[row]*K (embedding gather), row m = b*256 + s
// AMODE 1: A row = Abase + ((row&255)*NB + (row>>8))*K (hb_all[t][b], row=b*TL+t)
// OMODE 0: fp32 at row*N+col   OMODE 2: bf16 scattered to packed gi layout
template <int AMODE, int OMODE>
__global__ __launch_bounds__(256) void gemm_bf16(
    const unsigned short* __restrict__ Abase, const int* __restrict__ idx,
    const unsigned short* __restrict__ W, const float* __restrict__ bias,
    void* __restrict__ Cout, int N) {
  __shared__ unsigned short lds_a[8 * 128 * 8];  // 16 KB
  __shared__ unsigned short lds_b[8 * 128 * 8];  // 16 KB
  const int t = threadIdx.x;
  const int n0 = blockIdx.x * 128;
  const int m0 = blockIdx.y * 128;
  const int w = t >> 6, l = t & 63;
  const int mq = (w & 1) * 64, nq = (w >> 1) * 64;
  const int l15 = l & 15, lh = l >> 4;

  const int sm = t & 127;
  const int sk = (t >> 7) * 4;
  const unsigned short* arow;
  if (AMODE == 0) {
    arow = Abase + (size_t)idx[m0 + sm] * Dh;
  } else {
    int row = m0 + sm;
    arow = Abase + ((size_t)(row & 255) * NB + (row >> 8)) * Dh;
  }
  const unsigned short* brow = W + (size_t)(n0 + sm) * Dh;

  f32x4 acc[4][4];
#pragma unroll
  for (int i = 0; i < 4; ++i)
#pragma unroll
    for (int j = 0; j < 4; ++j) acc[i][j] = (f32x4)0.f;

  for (int k0 = 0; k0 < Dh; k0 += 64) {
    __syncthreads();
#pragma unroll
    for (int i = 0; i < 4; ++i) {
      int kc = sk + i;
      *(uint4*)&lds_a[(kc * 128 + sm) * 8] = *(const uint4*)(arow + k0 + kc * 8);
      *(uint4*)&lds_b[(kc * 128 + sm) * 8] = *(const uint4*)(brow + k0 + kc * 8);
    }
    __syncthreads();
#pragma unroll
    for (int q = 0; q < 2; ++q) {
      bf16x8 af[4], bfr[4];
#pragma unroll
      for (int i = 0; i < 4; ++i)
        af[i] = *(const bf16x8*)&lds_a[((q * 4 + lh) * 128 + mq + i * 16 + l15) * 8];
#pragma unroll
      for (int j = 0; j < 4; ++j)
        bfr[j] = *(const bf16x8*)&lds_b[((q * 4 + lh) * 128 + nq + j * 16 + l15) * 8];
#pragma unroll
      for (int i = 0; i < 4; ++i)
#pragma unroll
        for (int j = 0; j < 4; ++j)
          acc[i][j] = __builtin_amdgcn_mfma_f32_16x16x32_bf16(af[i], bfr[j], acc[i][j], 0, 0, 0);
    }
  }

#pragma unroll
  for (int j = 0; j < 4; ++j) {
    const int col = n0 + nq + j * 16 + l15;
    const float bv = bias[col];
#pragma unroll
    for (int i = 0; i < 4; ++i) {
#pragma unroll
      for (int r = 0; r < 4; ++r) {
        const int row = m0 + mq + i * 16 + lh * 4 + r;
        const float v = acc[i][j][r] + bv;
        if (OMODE == 0) {
          ((float*)Cout)[(size_t)row * N + col] = v;
        } else {
          const int b = row >> 8, s = row & 255;      // row = b*256 + s
          const int g = col >> 9, d = col & 511;
          const int dt = d >> 5, nn_ = (d >> 4) & 1, cl = d & 15;
          ((unsigned short*)Cout)[((((size_t)s * NB + b) * 16 + dt) * 16 + cl) * 8 + nn_ * 3 + g] = f2bf(v);
        }
      }
    }
  }
}

// ---- One GRU step, one wave per WG. 256 WGs x 64 thr = 1 wave/CU. ----
// Wave owns 16 batches x 32 d x 3 gates. W from packed lane-major layout:
// every B-load is a fully-coalesced 1KB instruction; wave's 96KB slice is
// contiguous and constant across steps -> L2-resident. No LDS, gates lane-local.
__global__ __launch_bounds__(64, 1) void gru_step3(
    const unsigned short* __restrict__ Wpk,  // [dt][6][16][64][8]
    const unsigned short* __restrict__ gi,   // packed [s][b][dt][l15][8] (incl. bih)
    const float* __restrict__ bhh,
    const float* __restrict__ h32_in, float* __restrict__ h32_out,
    const unsigned short* __restrict__ hb_in, unsigned short* __restrict__ hb_out,
    int s) {
  const int wt = blockIdx.x;               // 0..255
  const int b0 = (wt >> 4) * 16;
  const int dt = wt & 15, d0 = dt * 32;
  const int l = threadIdx.x & 63, l15 = l & 15, lh = l >> 4;

  // A-fragments: h rows b0+l15, k = kk*32 + lh*8
  bf16x8 af[16];
#pragma unroll
  for (int kk = 0; kk < 16; ++kk)
    af[kk] = *(const bf16x8*)(hb_in + (size_t)(b0 + l15) * Dh + kk * 32 + lh * 8);

  // gi packed loads: one uint4 per r
  uint4 gpr[4];
#pragma unroll
  for (int r = 0; r < 4; ++r)
    gpr[r] = *(const uint4*)(gi + ((((size_t)s * NB + b0 + lh * 4 + r) * 16 + dt) * 16 + l15) * 8);

  // fp32 h carry
  float hp[2][4];
#pragma unroll
  for (int n = 0; n < 2; ++n)
#pragma unroll
    for (int r = 0; r < 4; ++r)
      hp[n][r] = h32_in[(size_t)(b0 + lh * 4 + r) * Dh + d0 + n * 16 + l15];

  f32x4 acc[2][3];
#pragma unroll
  for (int n = 0; n < 2; ++n)
#pragma unroll
    for (int g = 0; g < 3; ++g) acc[n][g] = (f32x4)0.f;

  const unsigned short* wb = Wpk + ((size_t)dt * 6144 + l) * 8;  // + (slot*16+kk)*64*8
#pragma unroll
  for (int n = 0; n < 2; ++n)
#pragma unroll
    for (int g = 0; g < 3; ++g) {
      const int slot = n * 3 + g;
      bf16x8 bv[16];
#pragma unroll
      for (int kk = 0; kk < 16; ++kk)
        bv[kk] = *(const bf16x8*)(wb + (size_t)(slot * 16 + kk) * 64 * 8);
#pragma unroll
      for (int kk = 0; kk < 16; ++kk)
        acc[n][g] = __builtin_amdgcn_mfma_f32_16x16x32_bf16(af[kk], bv[kk], acc[n][g], 0, 0, 0);
    }

  // gates: lane-local. D row (batch) = lh*4+r, col = l15.
#pragma unroll
  for (int n = 0; n < 2; ++n) {
    const int d = d0 + n * 16 + l15;
    const float br = bhh[d], bz = bhh[512 + d], bn = bhh[1024 + d];
#pragma unroll
    for (int r = 0; r < 4; ++r) {
      const unsigned short* gp = (const unsigned short*)&gpr[r];
      const float gir = bf2f(gp[n * 3 + 0]);
      const float giz = bf2f(gp[n * 3 + 1]);
      const float gin = bf2f(gp[n * 3 + 2]);
      const float rr = 1.f / (1.f + __expf(-(gir + acc[n][0][r] + br)));
      const float zz = 1.f / (1.f + __expf(-(giz + acc[n][1][r] + bz)));
      const float x2 = gin + rr * (acc[n][2][r] + bn);
      const float nn = 1.f - 2.f / (__expf(2.f * x2) + 1.f);  // tanh
      const float o = (1.f - zz) * nn + zz * hp[n][r];
      const int b = b0 + lh * 4 + r;
      h32_out[(size_t)b * Dh + d] = o;
      hb_out[(size_t)b * Dh + d] = f2bf(o);
    }
  }
}

// in-place log_softmax over last dim (512); one wave per row
__global__ __launch_bounds__(256) void logsoftmax512(float* __restrict__ x) {
  const int row = blockIdx.x * 4 + (threadIdx.x >> 6);
  const int lane = threadIdx.x & 63;
  float* p = x + (size_t)row * NV + lane * 8;
  float4 v0 = *(const float4*)p;
  float4 v1 = *(const float4*)(p + 4);
  float m = fmaxf(fmaxf(fmaxf(v0.x, v0.y), fmaxf(v0.z, v0.w)),
                  fmaxf(fmaxf(v1.x, v1.y), fmaxf(v1.z, v1.w)));
#pragma unroll
  for (int o = 1; o < 64; o <<= 1) m = fmaxf(m, __shfl_xor(m, o, 64));
  float s = expf(v0.x - m) + expf(v0.y - m) + expf(v0.z - m) + expf(v0.w - m) +
            expf(v1.x - m) + expf(v1.y - m) + expf(v1.z - m) + expf(v1.w - m);
#pragma unroll
  for (int o = 1; o < 64; o <<= 1) s += __shfl_xor(s, o, 64);
  const float ls = m + logf(s);
  v0.x -= ls; v0.y -= ls; v0.z -= ls; v0.w -= ls;
  v1.x -= ls; v1.y -= ls; v1.z -= ls; v1.w -= ls;
  *(float4*)p = v0;
  *(float4*)(p + 4) = v1;
}

extern "C" void kernel_launch(void* const* d_in, const int* in_sizes, int n_in,
                              void* d_out, int out_size, void* d_ws, size_t ws_size,
                              hipStream_t stream) {
  (void)in_sizes; (void)n_in; (void)out_size; (void)ws_size;
  const int* src = (const int*)d_in[0];
  const int* trg = (const int*)d_in[1];
  const float* enc_emb = (const float*)d_in[4];
  const float* enc_Wih = (const float*)d_in[5];
  const float* enc_Whh = (const float*)d_in[6];
  const float* enc_bih = (const float*)d_in[7];
  const float* enc_bhh = (const float*)d_in[8];
  const float* dec_emb = (const float*)d_in[9];
  const float* dec_Wih = (const float*)d_in[10];
  const float* dec_Whh = (const float*)d_in[11];
  const float* dec_bih = (const float*)d_in[12];
  const float* dec_bhh = (const float*)d_in[13];
  const float* out_W = (const float*)d_in[14];
  const float* out_b = (const float*)d_in[15];

  char* ws = (char*)d_ws;
  size_t off = 0;
  auto alloc = [&](size_t bytes) -> char* {
    char* p = ws + off;
    off += (bytes + 255) & ~(size_t)255;
    return p;
  };
  typedef unsigned short u16;
  u16* gi = (u16*)alloc((size_t)NB * SL * 16 * 16 * 8 * 2);  // 268 MB packed
  u16* hb_all = (u16*)alloc((size_t)TL * NB * Dh * 2);       // 67 MB
  float* h32a = (float*)alloc((size_t)NB * Dh * 4);
  float* h32b = (float*)alloc((size_t)NB * Dh * 4);
  u16* hb0 = (u16*)alloc((size_t)NB * Dh * 2);
  u16* hb1 = (u16*)alloc((size_t)NB * Dh * 2);
  u16* embB_e = (u16*)alloc((size_t)NV * Dh * 2);
  u16* embB_d = (u16*)alloc((size_t)NV * Dh * 2);            // relu pre-applied
  u16* WihB_e = (u16*)alloc((size_t)G3 * Dh * 2);
  u16* WhhB_e = (u16*)alloc((size_t)G3 * Dh * 2);
  u16* WihB_d = (u16*)alloc((size_t)G3 * Dh * 2);
  u16* WhhB_d = (u16*)alloc((size_t)G3 * Dh * 2);
  u16* outWB = (u16*)alloc((size_t)NV * Dh * 2);
  u16* Wpk_e = (u16*)alloc((size_t)16 * 6 * 16 * 64 * 8 * 2);  // 1.57 MB
  u16* Wpk_d = (u16*)alloc((size_t)16 * 6 * 16 * 64 * 8 * 2);

  cvt_bf16<<<(NV * Dh / 4 + 255) / 256, 256, 0, stream>>>(enc_emb, embB_e, NV * Dh / 4, 0);
  cvt_bf16<<<(NV * Dh / 4 + 255) / 256, 256, 0, stream>>>(dec_emb, embB_d, NV * Dh / 4, 1);
  cvt_bf16<<<(G3 * Dh / 4 + 255) / 256, 256, 0, stream>>>(enc_Wih, WihB_e, G3 * Dh / 4, 0);
  cvt_bf16<<<(G3 * Dh / 4 + 255) / 256, 256, 0, stream>>>(enc_Whh, WhhB_e, G3 * Dh / 4, 0);
  cvt_bf16<<<(G3 * Dh / 4 + 255) / 256, 256, 0, stream>>>(dec_Wih, WihB_d, G3 * Dh / 4, 0);
  cvt_bf16<<<(G3 * Dh / 4 + 255) / 256, 256, 0, stream>>>(dec_Whh, WhhB_d, G3 * Dh / 4, 0);
  cvt_bf16<<<(NV * Dh / 4 + 255) / 256, 256, 0, stream>>>(out_W, outWB, NV * Dh / 4, 0);
  pack_whh<<<384, 256, 0, stream>>>(WhhB_e, Wpk_e);
  pack_whh<<<384, 256, 0, stream>>>(WhhB_d, Wpk_d);
  hipMemsetAsync(h32a, 0, (size_t)NB * Dh * 4, stream);  // fp32 h0 = 0
  hipMemsetAsync(hb0, 0, (size_t)NB * Dh * 2, stream);   // bf16 h0 = 0

  // encoder gi (packed layout)
  dim3 ggi(G3 / 128, NB * SL / 128);
  gemm_bf16<0, 2><<<ggi, 256, 0, stream>>>(embB_e, src, WihB_e, enc_bih, gi, G3);

  // ---- encoder recurrence: 256 lean per-step launches ----
  for (int s = 0; s < SL; ++s) {
    const float* i32 = (s & 1) ? h32b : h32a;
    float* o32 = (s & 1) ? h32a : h32b;
    const u16* ib = (s & 1) ? hb1 : hb0;
    u16* ob = (s & 1) ? hb0 : hb1;
    gru_step3<<<dim3(256), 64, 0, stream>>>(Wpk_e, gi, enc_bhh, i32, o32, ib, ob, s);
  }
  // SL=256 even -> final encoder state in h32a / hb0

  // decoder gi (packed layout; stream-ordered after encoder reads done)
  gemm_bf16<0, 2><<<ggi, 256, 0, stream>>>(embB_d, trg, WihB_d, dec_bih, gi, G3);

  // ---- decoder recurrence: h archived directly into hb_all ----
  for (int s = 0; s < TL; ++s) {
    const float* i32 = (s & 1) ? h32b : h32a;
    float* o32 = (s & 1) ? h32a : h32b;
    const u16* ib = (s == 0) ? hb0 : (hb_all + (size_t)(s - 1) * NB * Dh);
    u16* ob = hb_all + (size_t)s * NB * Dh;
    gru_step3<<<dim3(256), 64, 0, stream>>>(Wpk_d, gi, dec_bhh, i32, o32, ib, ob, s);
  }

  // logits = hb_all @ out_W^T + out_b -> d_out (fp32), then log_softmax
  dim3 glg(NV / 128, NB * TL / 128);
  gemm_bf16<1, 0><<<glg, 256, 0, stream>>>(hb_all, nullptr, outWB, out_b, d_out, NV);
  logsoftmax512<<<NB * TL / 4, 256, 0, stream>>>((float*)d_out);
}